// Round 14
// baseline (85.161 us; speedup 1.0000x reference)
//
#include <hip/hip_runtime.h>
#include <hip/hip_bf16.h>

typedef float f32x4 __attribute__((ext_vector_type(4)));
typedef short bf16x8 __attribute__((ext_vector_type(8)));
typedef short bf16x4 __attribute__((ext_vector_type(4)));
typedef unsigned short u16;

#define CS_BLOCKS 1024

// ws layout (bytes), all 512-aligned
#define WS_PART 0         // 1024 * 128 f32 = 524288
#define WS_GNN  524288    // 128 f32 = 512
#define WS_W1F  524800    // 65536
#define WS_W2F  590336    // 131072
#define WS_W3F  721408    // 65536
#define WS_WARM 786944    // 128 B

__device__ __forceinline__ u16 f2bf(float f) {
    __hip_bfloat16 h = __float2bfloat16(f);
    return *reinterpret_cast<u16*>(&h);
}

__device__ __forceinline__ bf16x8 pack8(f32x4 a, f32x4 b) {
    union { bf16x8 v; __hip_bfloat162 h[4]; } u;
    u.h[0] = __float22bfloat162_rn(make_float2(a[0], a[1]));
    u.h[1] = __float22bfloat162_rn(make_float2(a[2], a[3]));
    u.h[2] = __float22bfloat162_rn(make_float2(b[0], b[1]));
    u.h[3] = __float22bfloat162_rn(make_float2(b[2], b[3]));
    return u.v;
}

__device__ __forceinline__ bf16x4 pack4(f32x4 a) {
    union { bf16x4 v; __hip_bfloat162 h[2]; } u;
    u.h[0] = __float22bfloat162_rn(make_float2(a[0], a[1]));
    u.h[1] = __float22bfloat162_rn(make_float2(a[2], a[3]));
    return u.v;
}

// ---------------------------------------------------------------------------
// Kernel A: [0,1024): colsum partials of x (f32x4, 8 rows in flight).
//           [1024,1152): repack Wf1/Wf2/Wf3 -> MFMA-frag-ordered bf16.
//           [1152,1184): warm Wc1/Wc2 into L2/L3 for k_gnn's serial matvecs.
// ---------------------------------------------------------------------------
__global__ __launch_bounds__(256) void k_prep(
    const float* __restrict__ x,
    const float* __restrict__ Wf1, const float* __restrict__ Wf2,
    const float* __restrict__ Wf3,
    const float* __restrict__ Wc1, const float* __restrict__ Wc2,
    float* __restrict__ part, u16* __restrict__ w1f, u16* __restrict__ w2f,
    u16* __restrict__ w3f, float* __restrict__ warm, int n)
{
    __shared__ float smem[1024];
    int b = blockIdx.x, t = threadIdx.x;
    if (b < CS_BLOCKS) {
        int col4 = t & 31, rowo = t >> 5;       // col4: 16B chunk, rowo: 0..7
        int rpb = (n + CS_BLOCKS - 1) / CS_BLOCKS;
        int start = b * rpb;
        int end = min(start + rpb, n);
        f32x4 acc = {0.f, 0.f, 0.f, 0.f};
        #pragma unroll 4
        for (int r = start + rowo; r < end; r += 8)
            acc += *(const f32x4*)(x + (long)r * 128 + col4 * 4);
        *(f32x4*)&smem[rowo * 128 + col4 * 4] = acc;
        __syncthreads();
        if (t < 128) {
            float s = 0.f;
            #pragma unroll
            for (int i = 0; i < 8; ++i) s += smem[i * 128 + t];
            part[b * 128 + t] = s;
        }
    } else if (b < CS_BLOCKS + 128) {
        int e0 = ((b - CS_BLOCKS) * 256 + t) * 4; // 131072 elems total
        #pragma unroll
        for (int i = 0; i < 4; ++i) {
            int e = e0 + i;
            u16* dst; const float* src; int KS, NW;
            if (e < 32768)      { dst = w1f; src = Wf1; KS = 4; NW = 256; }
            else if (e < 98304) { dst = w2f; src = Wf2; KS = 8; NW = 256; e -= 32768; }
            else                { dst = w3f; src = Wf3; KS = 8; NW = 128; e -= 98304; }
            int fi = e >> 9, within = e & 511;
            int lane = within >> 3, j = within & 7;
            int nt = fi / KS, k = fi - nt * KS;
            int nn = nt * 16 + (lane & 15);
            int kk = k * 32 + ((lane >> 4) & 3) * 8 + j;
            dst[fi * 512 + within] = f2bf(src[kk * NW + nn]);
        }
    } else {
        // L2/L3 warm of Wc1 + Wc2: 2048 f32/block
        int idx = b - (CS_BLOCKS + 128);
        int base = idx * 2048 + t * 8;
        f32x4 a0, a1;
        if (base < 32768) {
            a0 = *(const f32x4*)(Wc1 + base);
            a1 = *(const f32x4*)(Wc1 + base + 4);
        } else {
            a0 = *(const f32x4*)(Wc2 + base - 32768);
            a1 = *(const f32x4*)(Wc2 + base - 32768 + 4);
        }
        float s = a0[0]+a0[1]+a0[2]+a0[3]+a1[0]+a1[1]+a1[2]+a1[3];
        smem[t] = s;
        __syncthreads();
        for (int o = 128; o > 0; o >>= 1) {
            if (t < o) smem[t] += smem[t + o];
            __syncthreads();
        }
        if (t == 0) warm[idx] = smem[0];
    }
}

// ---------------------------------------------------------------------------
// Kernel B: reduce colsum partials -> colmean, tiny GCN chain in f32.
// ---------------------------------------------------------------------------
__device__ __forceinline__ float block_sum(float v, float* wred, int t) {
    #pragma unroll
    for (int o = 32; o > 0; o >>= 1) v += __shfl_xor(v, o);
    if ((t & 63) == 0) wred[t >> 6] = v;
    __syncthreads();
    float s = wred[0] + wred[1] + wred[2] + wred[3];
    __syncthreads();
    return s;
}

__global__ __launch_bounds__(256) void k_gnn(
    const float* __restrict__ part,
    const float* __restrict__ Wc1, const float* __restrict__ bc1,
    const float* __restrict__ Wc2, const float* __restrict__ bc2,
    const float* __restrict__ g1,  const float* __restrict__ be1,
    const float* __restrict__ g2,  const float* __restrict__ be2,
    float* __restrict__ gnn, int n)
{
    int t = threadIdx.x;
    __shared__ float cm[128];
    __shared__ float hv[256];
    __shared__ float red[256];
    __shared__ float wred[4];
    __shared__ float red16[16][128];

    {   // partial reduce: CS_BLOCKS partials of 128 cols
        int col8 = t & 15, rowo = t >> 4;
        f32x4 a0 = {0.f,0.f,0.f,0.f}, a1 = {0.f,0.f,0.f,0.f};
        #pragma unroll 8
        for (int p = rowo; p < CS_BLOCKS; p += 16) {
            const f32x4* q = (const f32x4*)(part + p * 128 + col8 * 8);
            a0 += q[0]; a1 += q[1];
        }
        *(f32x4*)&red16[rowo][col8 * 8]     = a0;
        *(f32x4*)&red16[rowo][col8 * 8 + 4] = a1;
        __syncthreads();
        if (t < 128) {
            float s = 0.f;
            #pragma unroll
            for (int i = 0; i < 16; ++i) s += red16[i][t];
            cm[t] = s / (float)n;
        }
    }
    __syncthreads();

    // mv1: v = relu(cm @ Wc1 + bc1)
    float v = bc1[t];
    #pragma unroll 8
    for (int i = 0; i < 128; ++i) v += cm[i] * Wc1[i * 256 + t];
    v = fmaxf(v, 0.f);

    // LN over 256
    float mu = block_sum(v, wred, t) * (1.f / 256.f);
    float d = v - mu;
    float var = block_sum(d * d, wred, t) * (1.f / 256.f);
    hv[t] = d * rsqrtf(var + 1e-5f) * g1[t] + be1[t];
    __syncthreads();

    // mv2 split-K
    {
        int col = t & 127, half = t >> 7;
        float p = 0.f;
        #pragma unroll 8
        for (int i = half * 128; i < half * 128 + 128; ++i)
            p += hv[i] * Wc2[i * 128 + col];
        red[t] = p;
    }
    __syncthreads();
    float v2 = 0.f;
    bool lo = (t < 128);
    if (lo) v2 = bc2[t] + red[t] + red[t + 128];

    // LN over 128
    float mu2 = block_sum(lo ? v2 : 0.f, wred, t) * (1.f / 128.f);
    float d2 = v2 - mu2;
    float var2 = block_sum(lo ? d2 * d2 : 0.f, wred, t) * (1.f / 128.f);
    if (lo) gnn[t] = d2 * rsqrtf(var2 + 1e-5f) * g2[t] + be2[t];
}

// ---------------------------------------------------------------------------
// Kernel C: fused 3-layer MLP, BM=64, 8 waves as a 2x4 grid (wm,wn):
//   wm = w>>2 owns rows [wm*32, +32);  wn = w&3 owns cols [wn*64, +64)
//   (L1/L2) and [wn*32, +32) (L3).
// Each wave reads only ITS 32-row half of xs/h1/h2 -> LDS read bytes per
// block halve vs r13 (the measured binder). Same MFMA count; weight frags
// now loaded by 2 waves each (L2 traffic x2, still under L2 BW).
// Fragment-ordered LDS (r12/r13, conflict-free). 80 KB, no alias.
// ---------------------------------------------------------------------------
__global__ __launch_bounds__(512) void k_main(
    const float* __restrict__ x,
    const float* __restrict__ bf1v, const float* __restrict__ bf2v,
    const float* __restrict__ bf3v,
    const u16* __restrict__ w1f, const u16* __restrict__ w2f,
    const u16* __restrict__ w3f,
    const float* __restrict__ gnn,
    float* __restrict__ out, int n)
{
    __shared__ __align__(16) u16 xsf[16 * 512];  // 16 KB
    __shared__ __align__(16) u16 h1f[32 * 512];  // 32 KB
    __shared__ __align__(16) u16 h2f[32 * 512];  // 32 KB

    int t = threadIdx.x;
    int row0 = blockIdx.x * 64;
    int w = t >> 6, lane = t & 63, lr = lane & 15, lq = lane >> 4;
    int wm = w >> 2, wn = w & 3;

    // ---- stage x tile -> xsf (fragment order): warp w fills frag w*2+it ----
    #pragma unroll
    for (int it = 0; it < 2; ++it) {
        int f = w * 2 + it;                      // frag = (mt = f>>2, k = f&3)
        int grow = row0 + (f >> 2) * 16 + lr;
        f32x4 f0 = {0.f,0.f,0.f,0.f}, f1 = {0.f,0.f,0.f,0.f};
        if (grow < n) {
            const float* p = x + (long)grow * 128 + (f & 3) * 32 + lq * 8;
            f0 = *(const f32x4*)p; f1 = *(const f32x4*)(p + 4);
        }
        *(bf16x8*)(&xsf[f * 512 + lane * 8]) = pack8(f0, f1);
    }
    __syncthreads();

    // ---- layer 1: h1 = relu(x @ Wf1 + bf1): rows [wm*32,+32), cols [wn*64,+64)
    {
        bf16x8 b1[4][4];
        const bf16x8* base = (const bf16x8*)w1f;
        #pragma unroll
        for (int nt = 0; nt < 4; ++nt)
            #pragma unroll
            for (int k = 0; k < 4; ++k)
                b1[nt][k] = base[(((wn * 4 + nt) * 4) + k) * 64 + lane];
        f32x4 bias1[4];
        #pragma unroll
        for (int nt = 0; nt < 4; ++nt)
            bias1[nt] = *(const f32x4*)(bf1v + wn * 64 + nt * 16 + lq * 4);

        #pragma unroll
        for (int ml = 0; ml < 2; ++ml) {
            int mt = wm * 2 + ml;
            bf16x8 a[4];
            #pragma unroll
            for (int k = 0; k < 4; ++k)
                a[k] = *(const bf16x8*)(&xsf[(mt * 4 + k) * 512 + lane * 8]);
            #pragma unroll
            for (int nt = 0; nt < 4; ++nt) {
                f32x4 acc = bias1[nt];
                #pragma unroll
                for (int k = 0; k < 4; ++k)   // swapped: C^T, lane=(col=lq*4+j, row=lr)
                    acc = __builtin_amdgcn_mfma_f32_16x16x32_bf16(b1[nt][k], a[k], acc, 0, 0, 0);
                acc[0] = fmaxf(acc[0], 0.f); acc[1] = fmaxf(acc[1], 0.f);
                acc[2] = fmaxf(acc[2], 0.f); acc[3] = fmaxf(acc[3], 0.f);
                // frag (mt, kk = wn*2 + (nt>>1)); l = lr + 16*((nt&1)*2 + (lq>>1))
                int kk = wn * 2 + (nt >> 1);
                int l = lr + 16 * ((nt & 1) * 2 + (lq >> 1));
                *(bf16x4*)(&h1f[(mt * 8 + kk) * 512 + l * 8 + (lq & 1) * 4]) = pack4(acc);
            }
        }
    }
    __syncthreads();

    // ---- layer 2: h2 = relu(h1 @ Wf2 + bf2): rows [wm*32,+32), cols [wn*64,+64)
    {
        f32x4 bias2[4];
        #pragma unroll
        for (int nt = 0; nt < 4; ++nt)
            bias2[nt] = *(const f32x4*)(bf2v + wn * 64 + nt * 16 + lq * 4);
        f32x4 acc2[2][4];
        #pragma unroll
        for (int ml = 0; ml < 2; ++ml)
            #pragma unroll
            for (int nt = 0; nt < 4; ++nt)
                acc2[ml][nt] = bias2[nt];

        const bf16x8* base2 = (const bf16x8*)w2f;
        #pragma unroll
        for (int c = 0; c < 4; ++c) {            // kk chunk = {c*2, c*2+1}
            bf16x8 bc[4][2];
            #pragma unroll
            for (int nt = 0; nt < 4; ++nt)
                #pragma unroll
                for (int k = 0; k < 2; ++k)
                    bc[nt][k] = base2[(((wn * 4 + nt) * 8) + c * 2 + k) * 64 + lane];
            #pragma unroll
            for (int ml = 0; ml < 2; ++ml) {
                int mt = wm * 2 + ml;
                bf16x8 a[2];
                #pragma unroll
                for (int k = 0; k < 2; ++k)
                    a[k] = *(const bf16x8*)(&h1f[(mt * 8 + c * 2 + k) * 512 + lane * 8]);
                #pragma unroll
                for (int nt = 0; nt < 4; ++nt)
                    #pragma unroll
                    for (int k = 0; k < 2; ++k)
                        acc2[ml][nt] = __builtin_amdgcn_mfma_f32_16x16x32_bf16(bc[nt][k], a[k], acc2[ml][nt], 0, 0, 0);
            }
        }

        #pragma unroll
        for (int ml = 0; ml < 2; ++ml) {
            int mt = wm * 2 + ml;
            #pragma unroll
            for (int nt = 0; nt < 4; ++nt) {
                f32x4 acc = acc2[ml][nt];
                acc[0] = fmaxf(acc[0], 0.f); acc[1] = fmaxf(acc[1], 0.f);
                acc[2] = fmaxf(acc[2], 0.f); acc[3] = fmaxf(acc[3], 0.f);
                int kk = wn * 2 + (nt >> 1);
                int l = lr + 16 * ((nt & 1) * 2 + (lq >> 1));
                *(bf16x4*)(&h2f[(mt * 8 + kk) * 512 + l * 8 + (lq & 1) * 4]) = pack4(acc);
            }
        }
    }
    __syncthreads();

    // ---- layer 3: out = (h2 @ Wf3 + bf3 + gnn)*0.5: rows [wm*32,+32),
    //      cols [wn*32,+32) ----
    {
        bf16x8 b3[2][8];
        const bf16x8* base3 = (const bf16x8*)w3f;
        #pragma unroll
        for (int nt = 0; nt < 2; ++nt)
            #pragma unroll
            for (int k = 0; k < 8; ++k)
                b3[nt][k] = base3[(((wn * 2 + nt) * 8) + k) * 64 + lane];
        f32x4 c3[2];
        #pragma unroll
        for (int nt = 0; nt < 2; ++nt) {
            int colb = wn * 32 + nt * 16 + lq * 4;
            c3[nt] = *(const f32x4*)(bf3v + colb) + *(const f32x4*)(gnn + colb);
        }

        #pragma unroll
        for (int ml = 0; ml < 2; ++ml) {
            int mt = wm * 2 + ml;
            bf16x8 a[8];
            #pragma unroll
            for (int k = 0; k < 8; ++k)
                a[k] = *(const bf16x8*)(&h2f[(mt * 8 + k) * 512 + lane * 8]);
            int grow = row0 + mt * 16 + lr;
            #pragma unroll
            for (int nt = 0; nt < 2; ++nt) {
                f32x4 acc = c3[nt];
                #pragma unroll
                for (int k = 0; k < 8; ++k)
                    acc = __builtin_amdgcn_mfma_f32_16x16x32_bf16(b3[nt][k], a[k], acc, 0, 0, 0);
                if (grow < n)
                    *(f32x4*)(out + (long)grow * 128 + wn * 32 + nt * 16 + lq * 4) = acc * 0.5f;
            }
        }
    }
}

extern "C" void kernel_launch(void* const* d_in, const int* in_sizes, int n_in,
                              void* d_out, int out_size, void* d_ws, size_t ws_size,
                              hipStream_t stream)
{
    const float* x   = (const float*)d_in[0];
    const float* Wc1 = (const float*)d_in[1];
    const float* bc1 = (const float*)d_in[2];
    const float* Wc2 = (const float*)d_in[3];
    const float* bc2 = (const float*)d_in[4];
    const float* g1  = (const float*)d_in[5];
    const float* be1 = (const float*)d_in[6];
    const float* g2  = (const float*)d_in[7];
    const float* be2 = (const float*)d_in[8];
    const float* Wf1 = (const float*)d_in[9];
    const float* b1  = (const float*)d_in[10];
    const float* Wf2 = (const float*)d_in[11];
    const float* b2  = (const float*)d_in[12];
    const float* Wf3 = (const float*)d_in[13];
    const float* b3  = (const float*)d_in[14];
    int n = in_sizes[0] / 128;

    char* ws = (char*)d_ws;
    float* part = (float*)(ws + WS_PART);
    float* gnn  = (float*)(ws + WS_GNN);
    u16*   w1f  = (u16*)(ws + WS_W1F);
    u16*   w2f  = (u16*)(ws + WS_W2F);
    u16*   w3f  = (u16*)(ws + WS_W3F);
    float* warm = (float*)(ws + WS_WARM);

    k_prep<<<CS_BLOCKS + 128 + 32, 256, 0, stream>>>(
        x, Wf1, Wf2, Wf3, Wc1, Wc2, part, w1f, w2f, w3f, warm, n);
    k_gnn<<<1, 256, 0, stream>>>(part, Wc1, bc1, Wc2, bc2, g1, be1, g2, be2, gnn, n);
    int nb = (n + 63) / 64;
    k_main<<<nb, 512, 0, stream>>>(x, b1, b2, b3, w1f, w2f, w3f, gnn, (float*)d_out, n);
}

// Round 15
// 77.680 us; speedup vs baseline: 1.0963x; 1.0963x over previous
//
#include <hip/hip_runtime.h>
#include <hip/hip_bf16.h>

typedef float f32x4 __attribute__((ext_vector_type(4)));
typedef short bf16x8 __attribute__((ext_vector_type(8)));
typedef short bf16x4 __attribute__((ext_vector_type(4)));
typedef unsigned short u16;

#define CS_BLOCKS 512

// ws layout (bytes), all 512-aligned
#define WS_PART 0         // 512 * 128 f32 = 262144
#define WS_GNN  262144    // 128 f32 = 512
#define WS_W1F  262656    // 65536
#define WS_W2F  328192    // 131072
#define WS_W3F  459264    // 65536
#define WS_WARM 524800    // 128 B

__device__ __forceinline__ u16 f2bf(float f) {
    __hip_bfloat16 h = __float2bfloat16(f);
    return *reinterpret_cast<u16*>(&h);
}

__device__ __forceinline__ bf16x8 pack8(f32x4 a, f32x4 b) {
    union { bf16x8 v; __hip_bfloat162 h[4]; } u;
    u.h[0] = __float22bfloat162_rn(make_float2(a[0], a[1]));
    u.h[1] = __float22bfloat162_rn(make_float2(a[2], a[3]));
    u.h[2] = __float22bfloat162_rn(make_float2(b[0], b[1]));
    u.h[3] = __float22bfloat162_rn(make_float2(b[2], b[3]));
    return u.v;
}

__device__ __forceinline__ bf16x4 pack4(f32x4 a) {
    union { bf16x4 v; __hip_bfloat162 h[2]; } u;
    u.h[0] = __float22bfloat162_rn(make_float2(a[0], a[1]));
    u.h[1] = __float22bfloat162_rn(make_float2(a[2], a[3]));
    return u.v;
}

// ---------------------------------------------------------------------------
// Kernel A: [0,512): colsum partials of x — 16 rows in flight, 2 independent
//           f32x4 accs per lane (12 iters vs 24: deeper memory-level ||ism).
//           [512,640): repack Wf1/Wf2/Wf3 -> MFMA-frag-ordered bf16.
//           [640,672): warm Wc1/Wc2 into L2/L3 for k_gnn's serial matvecs.
// ---------------------------------------------------------------------------
__global__ __launch_bounds__(256) void k_prep(
    const float* __restrict__ x,
    const float* __restrict__ Wf1, const float* __restrict__ Wf2,
    const float* __restrict__ Wf3,
    const float* __restrict__ Wc1, const float* __restrict__ Wc2,
    float* __restrict__ part, u16* __restrict__ w1f, u16* __restrict__ w2f,
    u16* __restrict__ w3f, float* __restrict__ warm, int n)
{
    __shared__ float smem[2048];
    int b = blockIdx.x, t = threadIdx.x;
    if (b < CS_BLOCKS) {
        int col8 = t & 15, rowo = t >> 4;       // 16 lanes x 32B = 512B row
        int rpb = (n + CS_BLOCKS - 1) / CS_BLOCKS;
        int start = b * rpb;
        int end = min(start + rpb, n);
        f32x4 a0 = {0.f,0.f,0.f,0.f}, a1 = {0.f,0.f,0.f,0.f};
        #pragma unroll 2
        for (int r = start + rowo; r < end; r += 16) {
            const f32x4* p = (const f32x4*)(x + (long)r * 128 + col8 * 8);
            a0 += p[0]; a1 += p[1];
        }
        *(f32x4*)&smem[rowo * 128 + col8 * 8]     = a0;
        *(f32x4*)&smem[rowo * 128 + col8 * 8 + 4] = a1;
        __syncthreads();
        if (t < 128) {
            float s = 0.f;
            #pragma unroll
            for (int i = 0; i < 16; ++i) s += smem[i * 128 + t];
            part[b * 128 + t] = s;
        }
    } else if (b < CS_BLOCKS + 128) {
        int e0 = ((b - CS_BLOCKS) * 256 + t) * 4; // 131072 elems total
        #pragma unroll
        for (int i = 0; i < 4; ++i) {
            int e = e0 + i;
            u16* dst; const float* src; int KS, NW;
            if (e < 32768)      { dst = w1f; src = Wf1; KS = 4; NW = 256; }
            else if (e < 98304) { dst = w2f; src = Wf2; KS = 8; NW = 256; e -= 32768; }
            else                { dst = w3f; src = Wf3; KS = 8; NW = 128; e -= 98304; }
            int fi = e >> 9, within = e & 511;
            int lane = within >> 3, j = within & 7;
            int nt = fi / KS, k = fi - nt * KS;
            int nn = nt * 16 + (lane & 15);
            int kk = k * 32 + ((lane >> 4) & 3) * 8 + j;
            dst[fi * 512 + within] = f2bf(src[kk * NW + nn]);
        }
    } else {
        // L2/L3 warm of Wc1 + Wc2: 2048 f32/block
        int idx = b - (CS_BLOCKS + 128);
        int base = idx * 2048 + t * 8;
        f32x4 a0, a1;
        if (base < 32768) {
            a0 = *(const f32x4*)(Wc1 + base);
            a1 = *(const f32x4*)(Wc1 + base + 4);
        } else {
            a0 = *(const f32x4*)(Wc2 + base - 32768);
            a1 = *(const f32x4*)(Wc2 + base - 32768 + 4);
        }
        float s = a0[0]+a0[1]+a0[2]+a0[3]+a1[0]+a1[1]+a1[2]+a1[3];
        smem[t] = s;
        __syncthreads();
        for (int o = 128; o > 0; o >>= 1) {
            if (t < o) smem[t] += smem[t + o];
            __syncthreads();
        }
        if (t == 0) warm[idx] = smem[0];
    }
}

// ---------------------------------------------------------------------------
// Kernel B: reduce colsum partials -> colmean, tiny GCN chain in f32.
// ---------------------------------------------------------------------------
__device__ __forceinline__ float block_sum(float v, float* wred, int t) {
    #pragma unroll
    for (int o = 32; o > 0; o >>= 1) v += __shfl_xor(v, o);
    if ((t & 63) == 0) wred[t >> 6] = v;
    __syncthreads();
    float s = wred[0] + wred[1] + wred[2] + wred[3];
    __syncthreads();
    return s;
}

__global__ __launch_bounds__(256) void k_gnn(
    const float* __restrict__ part,
    const float* __restrict__ Wc1, const float* __restrict__ bc1,
    const float* __restrict__ Wc2, const float* __restrict__ bc2,
    const float* __restrict__ g1,  const float* __restrict__ be1,
    const float* __restrict__ g2,  const float* __restrict__ be2,
    float* __restrict__ gnn, int n)
{
    int t = threadIdx.x;
    __shared__ float cm[128];
    __shared__ float hv[256];
    __shared__ float red[256];
    __shared__ float wred[4];
    __shared__ float red16[16][128];

    {   // partial reduce: CS_BLOCKS partials of 128 cols
        int col8 = t & 15, rowo = t >> 4;
        f32x4 a0 = {0.f,0.f,0.f,0.f}, a1 = {0.f,0.f,0.f,0.f};
        #pragma unroll 8
        for (int p = rowo; p < CS_BLOCKS; p += 16) {
            const f32x4* q = (const f32x4*)(part + p * 128 + col8 * 8);
            a0 += q[0]; a1 += q[1];
        }
        *(f32x4*)&red16[rowo][col8 * 8]     = a0;
        *(f32x4*)&red16[rowo][col8 * 8 + 4] = a1;
        __syncthreads();
        if (t < 128) {
            float s = 0.f;
            #pragma unroll
            for (int i = 0; i < 16; ++i) s += red16[i][t];
            cm[t] = s / (float)n;
        }
    }
    __syncthreads();

    // mv1: v = relu(cm @ Wc1 + bc1)
    float v = bc1[t];
    #pragma unroll 8
    for (int i = 0; i < 128; ++i) v += cm[i] * Wc1[i * 256 + t];
    v = fmaxf(v, 0.f);

    // LN over 256
    float mu = block_sum(v, wred, t) * (1.f / 256.f);
    float d = v - mu;
    float var = block_sum(d * d, wred, t) * (1.f / 256.f);
    hv[t] = d * rsqrtf(var + 1e-5f) * g1[t] + be1[t];
    __syncthreads();

    // mv2 split-K
    {
        int col = t & 127, half = t >> 7;
        float p = 0.f;
        #pragma unroll 8
        for (int i = half * 128; i < half * 128 + 128; ++i)
            p += hv[i] * Wc2[i * 128 + col];
        red[t] = p;
    }
    __syncthreads();
    float v2 = 0.f;
    bool lo = (t < 128);
    if (lo) v2 = bc2[t] + red[t] + red[t + 128];

    // LN over 128
    float mu2 = block_sum(lo ? v2 : 0.f, wred, t) * (1.f / 128.f);
    float d2 = v2 - mu2;
    float var2 = block_sum(lo ? d2 * d2 : 0.f, wred, t) * (1.f / 128.f);
    if (lo) gnn[t] = d2 * rsqrtf(var2 + 1e-5f) * g2[t] + be2[t];
}

// ---------------------------------------------------------------------------
// Kernel C: fused 3-layer MLP — r13 structure (best verified: 44.4 us).
// BM=64, 8 waves N-split, fragment-ordered LDS, 80 KB, no alias,
// no cross-barrier prefetch (r3/r5/r9/r14: load-count/pinning regressions).
// One change vs r13: L2's two half-loops merged — per mt, all 8 a-frags
// load in one batch (8 ds_read_b128 in flight) feeding 16 MFMAs.
// ---------------------------------------------------------------------------
__global__ __launch_bounds__(512) void k_main(
    const float* __restrict__ x,
    const float* __restrict__ bf1v, const float* __restrict__ bf2v,
    const float* __restrict__ bf3v,
    const u16* __restrict__ w1f, const u16* __restrict__ w2f,
    const u16* __restrict__ w3f,
    const float* __restrict__ gnn,
    float* __restrict__ out, int n)
{
    __shared__ __align__(16) u16 xsf[16 * 512];  // 16 KB
    __shared__ __align__(16) u16 h1f[32 * 512];  // 32 KB
    __shared__ __align__(16) u16 h2f[32 * 512];  // 32 KB

    int t = threadIdx.x;
    int row0 = blockIdx.x * 64;
    int w = t >> 6, lane = t & 63, lr = lane & 15, lq = lane >> 4;

    // ---- stage x tile -> xsf (fragment order): warp w fills frag w*2+it ----
    #pragma unroll
    for (int it = 0; it < 2; ++it) {
        int f = w * 2 + it;                      // frag = (mt = f>>2, k = f&3)
        int grow = row0 + (f >> 2) * 16 + lr;
        f32x4 f0 = {0.f,0.f,0.f,0.f}, f1 = {0.f,0.f,0.f,0.f};
        if (grow < n) {
            const float* p = x + (long)grow * 128 + (f & 3) * 32 + lq * 8;
            f0 = *(const f32x4*)p; f1 = *(const f32x4*)(p + 4);
        }
        *(bf16x8*)(&xsf[f * 512 + lane * 8]) = pack8(f0, f1);
    }
    __syncthreads();

    // ---- layer 1: h1 = relu(x @ Wf1 + bf1), wave cols [w*32, w*32+32) ----
    {
        bf16x8 b1[2][4];
        const bf16x8* base = (const bf16x8*)w1f;
        #pragma unroll
        for (int nt = 0; nt < 2; ++nt)
            #pragma unroll
            for (int k = 0; k < 4; ++k)
                b1[nt][k] = base[(((w * 2 + nt) * 4) + k) * 64 + lane];
        f32x4 bias1[2];
        #pragma unroll
        for (int nt = 0; nt < 2; ++nt)
            bias1[nt] = *(const f32x4*)(bf1v + w * 32 + nt * 16 + lq * 4);

        #pragma unroll
        for (int mt = 0; mt < 4; ++mt) {
            bf16x8 a[4];
            #pragma unroll
            for (int k = 0; k < 4; ++k)
                a[k] = *(const bf16x8*)(&xsf[(mt * 4 + k) * 512 + lane * 8]);
            #pragma unroll
            for (int nt = 0; nt < 2; ++nt) {
                f32x4 acc = bias1[nt];
                #pragma unroll
                for (int k = 0; k < 4; ++k)   // swapped: C^T, lane=(col=lq*4+j, row=lr)
                    acc = __builtin_amdgcn_mfma_f32_16x16x32_bf16(b1[nt][k], a[k], acc, 0, 0, 0);
                acc[0] = fmaxf(acc[0], 0.f); acc[1] = fmaxf(acc[1], 0.f);
                acc[2] = fmaxf(acc[2], 0.f); acc[3] = fmaxf(acc[3], 0.f);
                int l = lr + 16 * (nt * 2 + (lq >> 1));
                *(bf16x4*)(&h1f[(mt * 8 + w) * 512 + l * 8 + (lq & 1) * 4]) = pack4(acc);
            }
        }
    }
    __syncthreads();

    // ---- layer 2: h2 = relu(h1 @ Wf2 + bf2), wave cols [w*32, w*32+32) ----
    {
        f32x4 bias2[2];
        #pragma unroll
        for (int nt = 0; nt < 2; ++nt)
            bias2[nt] = *(const f32x4*)(bf2v + w * 32 + nt * 16 + lq * 4);
        f32x4 acc2[4][2];
        #pragma unroll
        for (int mt = 0; mt < 4; ++mt)
            #pragma unroll
            for (int nt = 0; nt < 2; ++nt)
                acc2[mt][nt] = bias2[nt];

        const bf16x8* base2 = (const bf16x8*)w2f;
        bf16x8 b2[2][8];
        #pragma unroll
        for (int nt = 0; nt < 2; ++nt)
            #pragma unroll
            for (int k = 0; k < 8; ++k)
                b2[nt][k] = base2[(((w * 2 + nt) * 8) + k) * 64 + lane];

        #pragma unroll
        for (int mt = 0; mt < 4; ++mt) {
            bf16x8 a[8];                          // all 8 k-frags in one batch
            #pragma unroll
            for (int k = 0; k < 8; ++k)
                a[k] = *(const bf16x8*)(&h1f[(mt * 8 + k) * 512 + lane * 8]);
            #pragma unroll
            for (int nt = 0; nt < 2; ++nt)
                #pragma unroll
                for (int k = 0; k < 8; ++k)
                    acc2[mt][nt] = __builtin_amdgcn_mfma_f32_16x16x32_bf16(b2[nt][k], a[k], acc2[mt][nt], 0, 0, 0);
        }

        #pragma unroll
        for (int mt = 0; mt < 4; ++mt) {
            #pragma unroll
            for (int nt = 0; nt < 2; ++nt) {
                f32x4 acc = acc2[mt][nt];
                acc[0] = fmaxf(acc[0], 0.f); acc[1] = fmaxf(acc[1], 0.f);
                acc[2] = fmaxf(acc[2], 0.f); acc[3] = fmaxf(acc[3], 0.f);
                int l = lr + 16 * (nt * 2 + (lq >> 1));
                *(bf16x4*)(&h2f[(mt * 8 + w) * 512 + l * 8 + (lq & 1) * 4]) = pack4(acc);
            }
        }
    }
    __syncthreads();

    // ---- layer 3: out = (h2 @ Wf3 + bf3 + gnn)*0.5, wave cols [w*16,+16) --
    {
        bf16x8 b3[8];
        const bf16x8* base3 = (const bf16x8*)w3f;
        #pragma unroll
        for (int k = 0; k < 8; ++k)
            b3[k] = base3[(w * 8 + k) * 64 + lane];
        f32x4 c3;
        {
            int colb = w * 16 + lq * 4;
            c3 = *(const f32x4*)(bf3v + colb) + *(const f32x4*)(gnn + colb);
        }

        #pragma unroll
        for (int mt = 0; mt < 4; ++mt) {
            bf16x8 a[8];
            #pragma unroll
            for (int k = 0; k < 8; ++k)
                a[k] = *(const bf16x8*)(&h2f[(mt * 8 + k) * 512 + lane * 8]);
            int grow = row0 + mt * 16 + lr;
            f32x4 acc = c3;
            #pragma unroll
            for (int k = 0; k < 8; ++k)
                acc = __builtin_amdgcn_mfma_f32_16x16x32_bf16(b3[k], a[k], acc, 0, 0, 0);
            if (grow < n)
                *(f32x4*)(out + (long)grow * 128 + w * 16 + lq * 4) = acc * 0.5f;
        }
    }
}

extern "C" void kernel_launch(void* const* d_in, const int* in_sizes, int n_in,
                              void* d_out, int out_size, void* d_ws, size_t ws_size,
                              hipStream_t stream)
{
    const float* x   = (const float*)d_in[0];
    const float* Wc1 = (const float*)d_in[1];
    const float* bc1 = (const float*)d_in[2];
    const float* Wc2 = (const float*)d_in[3];
    const float* bc2 = (const float*)d_in[4];
    const float* g1  = (const float*)d_in[5];
    const float* be1 = (const float*)d_in[6];
    const float* g2  = (const float*)d_in[7];
    const float* be2 = (const float*)d_in[8];
    const float* Wf1 = (const float*)d_in[9];
    const float* b1  = (const float*)d_in[10];
    const float* Wf2 = (const float*)d_in[11];
    const float* b2  = (const float*)d_in[12];
    const float* Wf3 = (const float*)d_in[13];
    const float* b3  = (const float*)d_in[14];
    int n = in_sizes[0] / 128;

    char* ws = (char*)d_ws;
    float* part = (float*)(ws + WS_PART);
    float* gnn  = (float*)(ws + WS_GNN);
    u16*   w1f  = (u16*)(ws + WS_W1F);
    u16*   w2f  = (u16*)(ws + WS_W2F);
    u16*   w3f  = (u16*)(ws + WS_W3F);
    float* warm = (float*)(ws + WS_WARM);

    k_prep<<<CS_BLOCKS + 128 + 32, 256, 0, stream>>>(
        x, Wf1, Wf2, Wf3, Wc1, Wc2, part, w1f, w2f, w3f, warm, n);
    k_gnn<<<1, 256, 0, stream>>>(part, Wc1, bc1, Wc2, bc2, g1, be1, g2, be2, gnn, n);
    int nb = (n + 63) / 64;
    k_main<<<nb, 512, 0, stream>>>(x, b1, b2, b3, w1f, w2f, w3f, gnn, (float*)d_out, n);
}

// Round 16
// 67.147 us; speedup vs baseline: 1.2683x; 1.1569x over previous
//
#include <hip/hip_runtime.h>
#include <hip/hip_bf16.h>

typedef float f32x4 __attribute__((ext_vector_type(4)));
typedef short bf16x8 __attribute__((ext_vector_type(8)));
typedef short bf16x4 __attribute__((ext_vector_type(4)));
typedef unsigned short u16;

#define CS_BLOCKS 512

// ws layout (bytes), all 512-aligned
#define WS_PART 0         // 512 * 128 f32 = 262144
#define WS_GNN  262144    // 128 f32 = 512
#define WS_W1F  262656    // 65536
#define WS_W2F  328192    // 131072
#define WS_W3F  459264    // 65536
#define WS_WARM 524800    // 128 B

__device__ __forceinline__ u16 f2bf(float f) {
    __hip_bfloat16 h = __float2bfloat16(f);
    return *reinterpret_cast<u16*>(&h);
}

__device__ __forceinline__ bf16x8 pack8(f32x4 a, f32x4 b) {
    union { bf16x8 v; __hip_bfloat162 h[4]; } u;
    u.h[0] = __float22bfloat162_rn(make_float2(a[0], a[1]));
    u.h[1] = __float22bfloat162_rn(make_float2(a[2], a[3]));
    u.h[2] = __float22bfloat162_rn(make_float2(b[0], b[1]));
    u.h[3] = __float22bfloat162_rn(make_float2(b[2], b[3]));
    return u.v;
}

__device__ __forceinline__ bf16x4 pack4(f32x4 a) {
    union { bf16x4 v; __hip_bfloat162 h[2]; } u;
    u.h[0] = __float22bfloat162_rn(make_float2(a[0], a[1]));
    u.h[1] = __float22bfloat162_rn(make_float2(a[2], a[3]));
    return u.v;
}

// ---------------------------------------------------------------------------
// Kernel A: [0,512): colsum partials of x (f32x4, 8 rows in flight).
//           [512,640): repack Wf1/Wf2/Wf3 -> MFMA-frag-ordered bf16.
//           [640,672): warm Wc1/Wc2 into L2/L3 for k_gnn's serial matvecs.
// ---------------------------------------------------------------------------
__global__ __launch_bounds__(256) void k_prep(
    const float* __restrict__ x,
    const float* __restrict__ Wf1, const float* __restrict__ Wf2,
    const float* __restrict__ Wf3,
    const float* __restrict__ Wc1, const float* __restrict__ Wc2,
    float* __restrict__ part, u16* __restrict__ w1f, u16* __restrict__ w2f,
    u16* __restrict__ w3f, float* __restrict__ warm, int n)
{
    __shared__ float smem[1024];
    int b = blockIdx.x, t = threadIdx.x;
    if (b < CS_BLOCKS) {
        int col4 = t & 31, rowo = t >> 5;       // col4: 16B chunk, rowo: 0..7
        int rpb = (n + CS_BLOCKS - 1) / CS_BLOCKS;
        int start = b * rpb;
        int end = min(start + rpb, n);
        f32x4 acc = {0.f, 0.f, 0.f, 0.f};
        #pragma unroll 4
        for (int r = start + rowo; r < end; r += 8)
            acc += *(const f32x4*)(x + (long)r * 128 + col4 * 4);
        *(f32x4*)&smem[rowo * 128 + col4 * 4] = acc;
        __syncthreads();
        if (t < 128) {
            float s = 0.f;
            #pragma unroll
            for (int i = 0; i < 8; ++i) s += smem[i * 128 + t];
            part[b * 128 + t] = s;
        }
    } else if (b < CS_BLOCKS + 128) {
        int e0 = ((b - CS_BLOCKS) * 256 + t) * 4; // 131072 elems total
        #pragma unroll
        for (int i = 0; i < 4; ++i) {
            int e = e0 + i;
            u16* dst; const float* src; int KS, NW;
            if (e < 32768)      { dst = w1f; src = Wf1; KS = 4; NW = 256; }
            else if (e < 98304) { dst = w2f; src = Wf2; KS = 8; NW = 256; e -= 32768; }
            else                { dst = w3f; src = Wf3; KS = 8; NW = 128; e -= 98304; }
            int fi = e >> 9, within = e & 511;
            int lane = within >> 3, j = within & 7;
            int nt = fi / KS, k = fi - nt * KS;
            int nn = nt * 16 + (lane & 15);
            int kk = k * 32 + ((lane >> 4) & 3) * 8 + j;
            dst[fi * 512 + within] = f2bf(src[kk * NW + nn]);
        }
    } else {
        // L2/L3 warm of Wc1 + Wc2: 2048 f32/block
        int idx = b - (CS_BLOCKS + 128);
        int base = idx * 2048 + t * 8;
        f32x4 a0, a1;
        if (base < 32768) {
            a0 = *(const f32x4*)(Wc1 + base);
            a1 = *(const f32x4*)(Wc1 + base + 4);
        } else {
            a0 = *(const f32x4*)(Wc2 + base - 32768);
            a1 = *(const f32x4*)(Wc2 + base - 32768 + 4);
        }
        float s = a0[0]+a0[1]+a0[2]+a0[3]+a1[0]+a1[1]+a1[2]+a1[3];
        smem[t] = s;
        __syncthreads();
        for (int o = 128; o > 0; o >>= 1) {
            if (t < o) smem[t] += smem[t + o];
            __syncthreads();
        }
        if (t == 0) warm[idx] = smem[0];
    }
}

// ---------------------------------------------------------------------------
// Kernel B: reduce colsum partials -> colmean, tiny GCN chain in f32.
// ---------------------------------------------------------------------------
__device__ __forceinline__ float block_sum(float v, float* wred, int t) {
    #pragma unroll
    for (int o = 32; o > 0; o >>= 1) v += __shfl_xor(v, o);
    if ((t & 63) == 0) wred[t >> 6] = v;
    __syncthreads();
    float s = wred[0] + wred[1] + wred[2] + wred[3];
    __syncthreads();
    return s;
}

__global__ __launch_bounds__(256) void k_gnn(
    const float* __restrict__ part,
    const float* __restrict__ Wc1, const float* __restrict__ bc1,
    const float* __restrict__ Wc2, const float* __restrict__ bc2,
    const float* __restrict__ g1,  const float* __restrict__ be1,
    const float* __restrict__ g2,  const float* __restrict__ be2,
    float* __restrict__ gnn, int n)
{
    int t = threadIdx.x;
    __shared__ float cm[128];
    __shared__ float hv[256];
    __shared__ float red[256];
    __shared__ float wred[4];
    __shared__ float red16[16][128];

    {   // partial reduce: CS_BLOCKS partials of 128 cols
        int col8 = t & 15, rowo = t >> 4;
        f32x4 a0 = {0.f,0.f,0.f,0.f}, a1 = {0.f,0.f,0.f,0.f};
        #pragma unroll 8
        for (int p = rowo; p < CS_BLOCKS; p += 16) {
            const f32x4* q = (const f32x4*)(part + p * 128 + col8 * 8);
            a0 += q[0]; a1 += q[1];
        }
        *(f32x4*)&red16[rowo][col8 * 8]     = a0;
        *(f32x4*)&red16[rowo][col8 * 8 + 4] = a1;
        __syncthreads();
        if (t < 128) {
            float s = 0.f;
            #pragma unroll
            for (int i = 0; i < 16; ++i) s += red16[i][t];
            cm[t] = s / (float)n;
        }
    }
    __syncthreads();

    // mv1: v = relu(cm @ Wc1 + bc1)
    float v = bc1[t];
    #pragma unroll 8
    for (int i = 0; i < 128; ++i) v += cm[i] * Wc1[i * 256 + t];
    v = fmaxf(v, 0.f);

    // LN over 256
    float mu = block_sum(v, wred, t) * (1.f / 256.f);
    float d = v - mu;
    float var = block_sum(d * d, wred, t) * (1.f / 256.f);
    hv[t] = d * rsqrtf(var + 1e-5f) * g1[t] + be1[t];
    __syncthreads();

    // mv2 split-K
    {
        int col = t & 127, half = t >> 7;
        float p = 0.f;
        #pragma unroll 8
        for (int i = half * 128; i < half * 128 + 128; ++i)
            p += hv[i] * Wc2[i * 128 + col];
        red[t] = p;
    }
    __syncthreads();
    float v2 = 0.f;
    bool lo = (t < 128);
    if (lo) v2 = bc2[t] + red[t] + red[t + 128];

    // LN over 128
    float mu2 = block_sum(lo ? v2 : 0.f, wred, t) * (1.f / 128.f);
    float d2 = v2 - mu2;
    float var2 = block_sum(lo ? d2 * d2 : 0.f, wred, t) * (1.f / 128.f);
    if (lo) gnn[t] = d2 * rsqrtf(var2 + 1e-5f) * g2[t] + be2[t];
}

// ---------------------------------------------------------------------------
// Kernel C: fused 3-layer MLP, BM=64, 8 waves, N-split — FRAGMENT-ORDERED LDS
// on the r8 base (separate buffers, NO alias, 3 barriers total). Fragment
// order removes bank conflicts (4.8M->800K) and all XOR address math.
// LDS 80 KB -> 2 blocks/CU. Best verified: k_main 44.4 us, total 66.9 us.
//   xs frag (mt,k):  xsf[(mt*4+k)*512 + lane*8 + j]
//   h  frag (mt,kk): hf [(mt*8+kk)*512 + lane*8 + j]
// Producer epilogue: lane (lq,lr) at (mt,nt) -> frag (mt, kk=w),
//   l = lr + 16*(nt*2 + (lq>>1)), byte off (lq&1)*8 (wave-contiguous 512B).
// Do NOT: hoist weight loads across barriers (r3/r5/r9), merge L2 halves
// (r15), alias h2 onto h1 (r11/r12), split M across waves (r14) — all
// measured regressions.
// ---------------------------------------------------------------------------
__global__ __launch_bounds__(512) void k_main(
    const float* __restrict__ x,
    const float* __restrict__ bf1v, const float* __restrict__ bf2v,
    const float* __restrict__ bf3v,
    const u16* __restrict__ w1f, const u16* __restrict__ w2f,
    const u16* __restrict__ w3f,
    const float* __restrict__ gnn,
    float* __restrict__ out, int n)
{
    __shared__ __align__(16) u16 xsf[16 * 512];  // 16 KB
    __shared__ __align__(16) u16 h1f[32 * 512];  // 32 KB
    __shared__ __align__(16) u16 h2f[32 * 512];  // 32 KB

    int t = threadIdx.x;
    int row0 = blockIdx.x * 64;
    int w = t >> 6, lane = t & 63, lr = lane & 15, lq = lane >> 4;

    // ---- stage x tile -> xsf (fragment order): warp w fills frag w*2+it ----
    #pragma unroll
    for (int it = 0; it < 2; ++it) {
        int f = w * 2 + it;                      // frag = (mt = f>>2, k = f&3)
        int grow = row0 + (f >> 2) * 16 + lr;
        f32x4 f0 = {0.f,0.f,0.f,0.f}, f1 = {0.f,0.f,0.f,0.f};
        if (grow < n) {
            const float* p = x + (long)grow * 128 + (f & 3) * 32 + lq * 8;
            f0 = *(const f32x4*)p; f1 = *(const f32x4*)(p + 4);
        }
        *(bf16x8*)(&xsf[f * 512 + lane * 8]) = pack8(f0, f1);
    }
    __syncthreads();

    // ---- layer 1: h1 = relu(x @ Wf1 + bf1), wave cols [w*32, w*32+32) ----
    {
        bf16x8 b1[2][4];
        const bf16x8* base = (const bf16x8*)w1f;
        #pragma unroll
        for (int nt = 0; nt < 2; ++nt)
            #pragma unroll
            for (int k = 0; k < 4; ++k)
                b1[nt][k] = base[(((w * 2 + nt) * 4) + k) * 64 + lane];
        f32x4 bias1[2];
        #pragma unroll
        for (int nt = 0; nt < 2; ++nt)
            bias1[nt] = *(const f32x4*)(bf1v + w * 32 + nt * 16 + lq * 4);

        #pragma unroll
        for (int mt = 0; mt < 4; ++mt) {
            bf16x8 a[4];
            #pragma unroll
            for (int k = 0; k < 4; ++k)
                a[k] = *(const bf16x8*)(&xsf[(mt * 4 + k) * 512 + lane * 8]);
            #pragma unroll
            for (int nt = 0; nt < 2; ++nt) {
                f32x4 acc = bias1[nt];
                #pragma unroll
                for (int k = 0; k < 4; ++k)   // swapped: C^T, lane=(col=lq*4+j, row=lr)
                    acc = __builtin_amdgcn_mfma_f32_16x16x32_bf16(b1[nt][k], a[k], acc, 0, 0, 0);
                acc[0] = fmaxf(acc[0], 0.f); acc[1] = fmaxf(acc[1], 0.f);
                acc[2] = fmaxf(acc[2], 0.f); acc[3] = fmaxf(acc[3], 0.f);
                int l = lr + 16 * (nt * 2 + (lq >> 1));
                *(bf16x4*)(&h1f[(mt * 8 + w) * 512 + l * 8 + (lq & 1) * 4]) = pack4(acc);
            }
        }
    }
    __syncthreads();

    // ---- layer 2: h2 = relu(h1 @ Wf2 + bf2), wave cols [w*32, w*32+32) ----
    {
        f32x4 bias2[2];
        #pragma unroll
        for (int nt = 0; nt < 2; ++nt)
            bias2[nt] = *(const f32x4*)(bf2v + w * 32 + nt * 16 + lq * 4);
        f32x4 acc2[4][2];
        #pragma unroll
        for (int mt = 0; mt < 4; ++mt)
            #pragma unroll
            for (int nt = 0; nt < 2; ++nt)
                acc2[mt][nt] = bias2[nt];

        const bf16x8* base2 = (const bf16x8*)w2f;
        bf16x8 b2a[2][4];
        #pragma unroll
        for (int nt = 0; nt < 2; ++nt)
            #pragma unroll
            for (int k = 0; k < 4; ++k)
                b2a[nt][k] = base2[(((w * 2 + nt) * 8) + k) * 64 + lane];

        #pragma unroll
        for (int mt = 0; mt < 4; ++mt) {          // half 0 (kk = 0..3)
            bf16x8 a[4];
            #pragma unroll
            for (int k = 0; k < 4; ++k)
                a[k] = *(const bf16x8*)(&h1f[(mt * 8 + k) * 512 + lane * 8]);
            #pragma unroll
            for (int nt = 0; nt < 2; ++nt)
                #pragma unroll
                for (int k = 0; k < 4; ++k)
                    acc2[mt][nt] = __builtin_amdgcn_mfma_f32_16x16x32_bf16(b2a[nt][k], a[k], acc2[mt][nt], 0, 0, 0);
        }

        bf16x8 b2b[2][4];
        #pragma unroll
        for (int nt = 0; nt < 2; ++nt)
            #pragma unroll
            for (int k = 0; k < 4; ++k)
                b2b[nt][k] = base2[(((w * 2 + nt) * 8) + 4 + k) * 64 + lane];

        #pragma unroll
        for (int mt = 0; mt < 4; ++mt) {          // half 1 (kk = 4..7)
            bf16x8 a[4];
            #pragma unroll
            for (int k = 0; k < 4; ++k)
                a[k] = *(const bf16x8*)(&h1f[(mt * 8 + 4 + k) * 512 + lane * 8]);
            #pragma unroll
            for (int nt = 0; nt < 2; ++nt)
                #pragma unroll
                for (int k = 0; k < 4; ++k)
                    acc2[mt][nt] = __builtin_amdgcn_mfma_f32_16x16x32_bf16(b2b[nt][k], a[k], acc2[mt][nt], 0, 0, 0);
        }

        // epilogue writes go to the separate h2f buffer — no guard needed
        #pragma unroll
        for (int mt = 0; mt < 4; ++mt) {
            #pragma unroll
            for (int nt = 0; nt < 2; ++nt) {
                f32x4 acc = acc2[mt][nt];
                acc[0] = fmaxf(acc[0], 0.f); acc[1] = fmaxf(acc[1], 0.f);
                acc[2] = fmaxf(acc[2], 0.f); acc[3] = fmaxf(acc[3], 0.f);
                int l = lr + 16 * (nt * 2 + (lq >> 1));
                *(bf16x4*)(&h2f[(mt * 8 + w) * 512 + l * 8 + (lq & 1) * 4]) = pack4(acc);
            }
        }
    }
    __syncthreads();

    // ---- layer 3: out = (h2 @ Wf3 + bf3 + gnn)*0.5, wave cols [w*16,+16) --
    {
        bf16x8 b3[8];
        const bf16x8* base3 = (const bf16x8*)w3f;
        #pragma unroll
        for (int k = 0; k < 8; ++k)
            b3[k] = base3[(w * 8 + k) * 64 + lane];
        f32x4 c3;
        {
            int colb = w * 16 + lq * 4;
            c3 = *(const f32x4*)(bf3v + colb) + *(const f32x4*)(gnn + colb);
        }

        #pragma unroll
        for (int mt = 0; mt < 4; ++mt) {
            bf16x8 a[8];
            #pragma unroll
            for (int k = 0; k < 8; ++k)
                a[k] = *(const bf16x8*)(&h2f[(mt * 8 + k) * 512 + lane * 8]);
            int grow = row0 + mt * 16 + lr;
            f32x4 acc = c3;
            #pragma unroll
            for (int k = 0; k < 8; ++k)
                acc = __builtin_amdgcn_mfma_f32_16x16x32_bf16(b3[k], a[k], acc, 0, 0, 0);
            if (grow < n)
                *(f32x4*)(out + (long)grow * 128 + w * 16 + lq * 4) = acc * 0.5f;
        }
    }
}

extern "C" void kernel_launch(void* const* d_in, const int* in_sizes, int n_in,
                              void* d_out, int out_size, void* d_ws, size_t ws_size,
                              hipStream_t stream)
{
    const float* x   = (const float*)d_in[0];
    const float* Wc1 = (const float*)d_in[1];
    const float* bc1 = (const float*)d_in[2];
    const float* Wc2 = (const float*)d_in[3];
    const float* bc2 = (const float*)d_in[4];
    const float* g1  = (const float*)d_in[5];
    const float* be1 = (const float*)d_in[6];
    const float* g2  = (const float*)d_in[7];
    const float* be2 = (const float*)d_in[8];
    const float* Wf1 = (const float*)d_in[9];
    const float* b1  = (const float*)d_in[10];
    const float* Wf2 = (const float*)d_in[11];
    const float* b2  = (const float*)d_in[12];
    const float* Wf3 = (const float*)d_in[13];
    const float* b3  = (const float*)d_in[14];
    int n = in_sizes[0] / 128;

    char* ws = (char*)d_ws;
    float* part = (float*)(ws + WS_PART);
    float* gnn  = (float*)(ws + WS_GNN);
    u16*   w1f  = (u16*)(ws + WS_W1F);
    u16*   w2f  = (u16*)(ws + WS_W2F);
    u16*   w3f  = (u16*)(ws + WS_W3F);
    float* warm = (float*)(ws + WS_WARM);

    k_prep<<<CS_BLOCKS + 128 + 32, 256, 0, stream>>>(
        x, Wf1, Wf2, Wf3, Wc1, Wc2, part, w1f, w2f, w3f, warm, n);
    k_gnn<<<1, 256, 0, stream>>>(part, Wc1, bc1, Wc2, bc2, g1, be1, g2, be2, gnn, n);
    int nb = (n + 63) / 64;
    k_main<<<nb, 512, 0, stream>>>(x, b1, b2, b3, w1f, w2f, w3f, gnn, (float*)d_out, n);
}

// Round 17
// 63.000 us; speedup vs baseline: 1.3517x; 1.0658x over previous
//
#include <hip/hip_runtime.h>
#include <hip/hip_bf16.h>

typedef float f32x4 __attribute__((ext_vector_type(4)));
typedef short bf16x8 __attribute__((ext_vector_type(8)));
typedef short bf16x4 __attribute__((ext_vector_type(4)));
typedef unsigned short u16;

#define CS_BLOCKS 512

// ws layout (bytes), all 512-aligned
#define WS_PART 0         // 512 * 128 f32 = 262144
#define WS_GNN  262144    // 128 f32 = 512
#define WS_W1F  262656    // 65536
#define WS_W2F  328192    // 131072
#define WS_W3F  459264    // 65536
#define WS_WARM 524800    // 128 B

__device__ __forceinline__ u16 f2bf(float f) {
    __hip_bfloat16 h = __float2bfloat16(f);
    return *reinterpret_cast<u16*>(&h);
}

__device__ __forceinline__ bf16x8 pack8(f32x4 a, f32x4 b) {
    union { bf16x8 v; __hip_bfloat162 h[4]; } u;
    u.h[0] = __float22bfloat162_rn(make_float2(a[0], a[1]));
    u.h[1] = __float22bfloat162_rn(make_float2(a[2], a[3]));
    u.h[2] = __float22bfloat162_rn(make_float2(b[0], b[1]));
    u.h[3] = __float22bfloat162_rn(make_float2(b[2], b[3]));
    return u.v;
}

__device__ __forceinline__ bf16x4 pack4(f32x4 a) {
    union { bf16x4 v; __hip_bfloat162 h[2]; } u;
    u.h[0] = __float22bfloat162_rn(make_float2(a[0], a[1]));
    u.h[1] = __float22bfloat162_rn(make_float2(a[2], a[3]));
    return u.v;
}

// ---------------------------------------------------------------------------
// Kernel A: [0,512): colsum partials of x (f32x4, 8 rows in flight).
//           [512,640): repack Wf1/Wf2/Wf3 -> MFMA-frag-ordered bf16.
//           [640,672): warm Wc1/Wc2 into L2/L3 for k_gnn's serial matvecs.
// (Byte-identical to r16 — do not touch.)
// ---------------------------------------------------------------------------
__global__ __launch_bounds__(256) void k_prep(
    const float* __restrict__ x,
    const float* __restrict__ Wf1, const float* __restrict__ Wf2,
    const float* __restrict__ Wf3,
    const float* __restrict__ Wc1, const float* __restrict__ Wc2,
    float* __restrict__ part, u16* __restrict__ w1f, u16* __restrict__ w2f,
    u16* __restrict__ w3f, float* __restrict__ warm, int n)
{
    __shared__ float smem[1024];
    int b = blockIdx.x, t = threadIdx.x;
    if (b < CS_BLOCKS) {
        int col4 = t & 31, rowo = t >> 5;       // col4: 16B chunk, rowo: 0..7
        int rpb = (n + CS_BLOCKS - 1) / CS_BLOCKS;
        int start = b * rpb;
        int end = min(start + rpb, n);
        f32x4 acc = {0.f, 0.f, 0.f, 0.f};
        #pragma unroll 4
        for (int r = start + rowo; r < end; r += 8)
            acc += *(const f32x4*)(x + (long)r * 128 + col4 * 4);
        *(f32x4*)&smem[rowo * 128 + col4 * 4] = acc;
        __syncthreads();
        if (t < 128) {
            float s = 0.f;
            #pragma unroll
            for (int i = 0; i < 8; ++i) s += smem[i * 128 + t];
            part[b * 128 + t] = s;
        }
    } else if (b < CS_BLOCKS + 128) {
        int e0 = ((b - CS_BLOCKS) * 256 + t) * 4; // 131072 elems total
        #pragma unroll
        for (int i = 0; i < 4; ++i) {
            int e = e0 + i;
            u16* dst; const float* src; int KS, NW;
            if (e < 32768)      { dst = w1f; src = Wf1; KS = 4; NW = 256; }
            else if (e < 98304) { dst = w2f; src = Wf2; KS = 8; NW = 256; e -= 32768; }
            else                { dst = w3f; src = Wf3; KS = 8; NW = 128; e -= 98304; }
            int fi = e >> 9, within = e & 511;
            int lane = within >> 3, j = within & 7;
            int nt = fi / KS, k = fi - nt * KS;
            int nn = nt * 16 + (lane & 15);
            int kk = k * 32 + ((lane >> 4) & 3) * 8 + j;
            dst[fi * 512 + within] = f2bf(src[kk * NW + nn]);
        }
    } else {
        // L2/L3 warm of Wc1 + Wc2: 2048 f32/block
        int idx = b - (CS_BLOCKS + 128);
        int base = idx * 2048 + t * 8;
        f32x4 a0, a1;
        if (base < 32768) {
            a0 = *(const f32x4*)(Wc1 + base);
            a1 = *(const f32x4*)(Wc1 + base + 4);
        } else {
            a0 = *(const f32x4*)(Wc2 + base - 32768);
            a1 = *(const f32x4*)(Wc2 + base - 32768 + 4);
        }
        float s = a0[0]+a0[1]+a0[2]+a0[3]+a1[0]+a1[1]+a1[2]+a1[3];
        smem[t] = s;
        __syncthreads();
        for (int o = 128; o > 0; o >>= 1) {
            if (t < o) smem[t] += smem[t + o];
            __syncthreads();
        }
        if (t == 0) warm[idx] = smem[0];
    }
}

// ---------------------------------------------------------------------------
// Kernel B: GCN chain — 512 threads (was 256): all serial latency chains
// halved. Partial-reduce over 32 row-groups (16 iters); mv1 split-K2
// (64 iters); mv2 split-K4 (64 iters). 8-wave block reductions.
// ---------------------------------------------------------------------------
__device__ __forceinline__ float block_sum8(float v, float* wred, int t) {
    #pragma unroll
    for (int o = 32; o > 0; o >>= 1) v += __shfl_xor(v, o);
    if ((t & 63) == 0) wred[t >> 6] = v;
    __syncthreads();
    float s = 0.f;
    #pragma unroll
    for (int i = 0; i < 8; ++i) s += wred[i];
    __syncthreads();
    return s;
}

__global__ __launch_bounds__(512) void k_gnn(
    const float* __restrict__ part,
    const float* __restrict__ Wc1, const float* __restrict__ bc1,
    const float* __restrict__ Wc2, const float* __restrict__ bc2,
    const float* __restrict__ g1,  const float* __restrict__ be1,
    const float* __restrict__ g2,  const float* __restrict__ be2,
    float* __restrict__ gnn, int n)
{
    int t = threadIdx.x;
    __shared__ float cm[128];
    __shared__ float hv[256];
    __shared__ float red[512];
    __shared__ float wred[8];
    __shared__ float red32[32][128];

    {   // partial reduce: 512 partials of 128 cols, 32 row-groups
        int col8 = t & 15, rowo = t >> 4;        // rowo: 0..31
        f32x4 a0 = {0.f,0.f,0.f,0.f}, a1 = {0.f,0.f,0.f,0.f};
        #pragma unroll 8
        for (int p = rowo; p < CS_BLOCKS; p += 32) {   // 16 iters
            const f32x4* q = (const f32x4*)(part + p * 128 + col8 * 8);
            a0 += q[0]; a1 += q[1];
        }
        *(f32x4*)&red32[rowo][col8 * 8]     = a0;
        *(f32x4*)&red32[rowo][col8 * 8 + 4] = a1;
        __syncthreads();
        if (t < 128) {
            float s = 0.f;
            #pragma unroll
            for (int i = 0; i < 32; ++i) s += red32[i][t];
            cm[t] = s / (float)n;
        }
    }
    __syncthreads();

    // mv1 split-K2: col = t&255, half = t>>8; 64 iters each
    {
        int col = t & 255, half = t >> 8;
        float p = 0.f;
        #pragma unroll 8
        for (int i = half * 64; i < half * 64 + 64; ++i)
            p += cm[i] * Wc1[i * 256 + col];
        red[t] = p;
    }
    __syncthreads();
    float v = 0.f;
    bool act = (t < 256);
    if (act) v = fmaxf(bc1[t] + red[t] + red[t + 256], 0.f);

    // LN over 256 (upper threads masked)
    float mu = block_sum8(act ? v : 0.f, wred, t) * (1.f / 256.f);
    float d = v - mu;
    float var = block_sum8(act ? d * d : 0.f, wred, t) * (1.f / 256.f);
    if (act) hv[t] = d * rsqrtf(var + 1e-5f) * g1[t] + be1[t];
    __syncthreads();

    // mv2 split-K4: col = t&127, q4 = t>>7; 64 iters each
    {
        int col = t & 127, q4 = t >> 7;
        float p = 0.f;
        #pragma unroll 8
        for (int i = q4 * 64; i < q4 * 64 + 64; ++i)
            p += hv[i] * Wc2[i * 128 + col];
        red[t] = p;
    }
    __syncthreads();
    float v2 = 0.f;
    bool lo = (t < 128);
    if (lo) v2 = bc2[t] + red[t] + red[t + 128] + red[t + 256] + red[t + 384];

    // LN over 128
    float mu2 = block_sum8(lo ? v2 : 0.f, wred, t) * (1.f / 128.f);
    float d2 = v2 - mu2;
    float var2 = block_sum8(lo ? d2 * d2 : 0.f, wred, t) * (1.f / 128.f);
    if (lo) gnn[t] = d2 * rsqrtf(var2 + 1e-5f) * g2[t] + be2[t];
}

// ---------------------------------------------------------------------------
// Kernel C: fused 3-layer MLP, BM=64, 8 waves, N-split — FRAGMENT-ORDERED LDS
// on the r8 base (separate buffers, NO alias, 3 barriers total). Fragment
// order removes bank conflicts (4.8M->800K) and all XOR address math.
// LDS 80 KB -> 2 blocks/CU. Best verified: k_main 44.4-44.5 us.
// Byte-identical to r16 — do NOT: hoist weight loads across barriers
// (r3/r5/r9), merge L2 halves (r15), alias h2 onto h1 (r11/r12), split M
// across waves (r14) — all measured regressions.
// ---------------------------------------------------------------------------
__global__ __launch_bounds__(512) void k_main(
    const float* __restrict__ x,
    const float* __restrict__ bf1v, const float* __restrict__ bf2v,
    const float* __restrict__ bf3v,
    const u16* __restrict__ w1f, const u16* __restrict__ w2f,
    const u16* __restrict__ w3f,
    const float* __restrict__ gnn,
    float* __restrict__ out, int n)
{
    __shared__ __align__(16) u16 xsf[16 * 512];  // 16 KB
    __shared__ __align__(16) u16 h1f[32 * 512];  // 32 KB
    __shared__ __align__(16) u16 h2f[32 * 512];  // 32 KB

    int t = threadIdx.x;
    int row0 = blockIdx.x * 64;
    int w = t >> 6, lane = t & 63, lr = lane & 15, lq = lane >> 4;

    // ---- stage x tile -> xsf (fragment order): warp w fills frag w*2+it ----
    #pragma unroll
    for (int it = 0; it < 2; ++it) {
        int f = w * 2 + it;                      // frag = (mt = f>>2, k = f&3)
        int grow = row0 + (f >> 2) * 16 + lr;
        f32x4 f0 = {0.f,0.f,0.f,0.f}, f1 = {0.f,0.f,0.f,0.f};
        if (grow < n) {
            const float* p = x + (long)grow * 128 + (f & 3) * 32 + lq * 8;
            f0 = *(const f32x4*)p; f1 = *(const f32x4*)(p + 4);
        }
        *(bf16x8*)(&xsf[f * 512 + lane * 8]) = pack8(f0, f1);
    }
    __syncthreads();

    // ---- layer 1: h1 = relu(x @ Wf1 + bf1), wave cols [w*32, w*32+32) ----
    {
        bf16x8 b1[2][4];
        const bf16x8* base = (const bf16x8*)w1f;
        #pragma unroll
        for (int nt = 0; nt < 2; ++nt)
            #pragma unroll
            for (int k = 0; k < 4; ++k)
                b1[nt][k] = base[(((w * 2 + nt) * 4) + k) * 64 + lane];
        f32x4 bias1[2];
        #pragma unroll
        for (int nt = 0; nt < 2; ++nt)
            bias1[nt] = *(const f32x4*)(bf1v + w * 32 + nt * 16 + lq * 4);

        #pragma unroll
        for (int mt = 0; mt < 4; ++mt) {
            bf16x8 a[4];
            #pragma unroll
            for (int k = 0; k < 4; ++k)
                a[k] = *(const bf16x8*)(&xsf[(mt * 4 + k) * 512 + lane * 8]);
            #pragma unroll
            for (int nt = 0; nt < 2; ++nt) {
                f32x4 acc = bias1[nt];
                #pragma unroll
                for (int k = 0; k < 4; ++k)   // swapped: C^T, lane=(col=lq*4+j, row=lr)
                    acc = __builtin_amdgcn_mfma_f32_16x16x32_bf16(b1[nt][k], a[k], acc, 0, 0, 0);
                acc[0] = fmaxf(acc[0], 0.f); acc[1] = fmaxf(acc[1], 0.f);
                acc[2] = fmaxf(acc[2], 0.f); acc[3] = fmaxf(acc[3], 0.f);
                int l = lr + 16 * (nt * 2 + (lq >> 1));
                *(bf16x4*)(&h1f[(mt * 8 + w) * 512 + l * 8 + (lq & 1) * 4]) = pack4(acc);
            }
        }
    }
    __syncthreads();

    // ---- layer 2: h2 = relu(h1 @ Wf2 + bf2), wave cols [w*32, w*32+32) ----
    {
        f32x4 bias2[2];
        #pragma unroll
        for (int nt = 0; nt < 2; ++nt)
            bias2[nt] = *(const f32x4*)(bf2v + w * 32 + nt * 16 + lq * 4);
        f32x4 acc2[4][2];
        #pragma unroll
        for (int mt = 0; mt < 4; ++mt)
            #pragma unroll
            for (int nt = 0; nt < 2; ++nt)
                acc2[mt][nt] = bias2[nt];

        const bf16x8* base2 = (const bf16x8*)w2f;
        bf16x8 b2a[2][4];
        #pragma unroll
        for (int nt = 0; nt < 2; ++nt)
            #pragma unroll
            for (int k = 0; k < 4; ++k)
                b2a[nt][k] = base2[(((w * 2 + nt) * 8) + k) * 64 + lane];

        #pragma unroll
        for (int mt = 0; mt < 4; ++mt) {          // half 0 (kk = 0..3)
            bf16x8 a[4];
            #pragma unroll
            for (int k = 0; k < 4; ++k)
                a[k] = *(const bf16x8*)(&h1f[(mt * 8 + k) * 512 + lane * 8]);
            #pragma unroll
            for (int nt = 0; nt < 2; ++nt)
                #pragma unroll
                for (int k = 0; k < 4; ++k)
                    acc2[mt][nt] = __builtin_amdgcn_mfma_f32_16x16x32_bf16(b2a[nt][k], a[k], acc2[mt][nt], 0, 0, 0);
        }

        bf16x8 b2b[2][4];
        #pragma unroll
        for (int nt = 0; nt < 2; ++nt)
            #pragma unroll
            for (int k = 0; k < 4; ++k)
                b2b[nt][k] = base2[(((w * 2 + nt) * 8) + 4 + k) * 64 + lane];

        #pragma unroll
        for (int mt = 0; mt < 4; ++mt) {          // half 1 (kk = 4..7)
            bf16x8 a[4];
            #pragma unroll
            for (int k = 0; k < 4; ++k)
                a[k] = *(const bf16x8*)(&h1f[(mt * 8 + 4 + k) * 512 + lane * 8]);
            #pragma unroll
            for (int nt = 0; nt < 2; ++nt)
                #pragma unroll
                for (int k = 0; k < 4; ++k)
                    acc2[mt][nt] = __builtin_amdgcn_mfma_f32_16x16x32_bf16(b2b[nt][k], a[k], acc2[mt][nt], 0, 0, 0);
        }

        // epilogue writes go to the separate h2f buffer — no guard needed
        #pragma unroll
        for (int mt = 0; mt < 4; ++mt) {
            #pragma unroll
            for (int nt = 0; nt < 2; ++nt) {
                f32x4 acc = acc2[mt][nt];
                acc[0] = fmaxf(acc[0], 0.f); acc[1] = fmaxf(acc[1], 0.f);
                acc[2] = fmaxf(acc[2], 0.f); acc[3] = fmaxf(acc[3], 0.f);
                int l = lr + 16 * (nt * 2 + (lq >> 1));
                *(bf16x4*)(&h2f[(mt * 8 + w) * 512 + l * 8 + (lq & 1) * 4]) = pack4(acc);
            }
        }
    }
    __syncthreads();

    // ---- layer 3: out = (h2 @ Wf3 + bf3 + gnn)*0.5, wave cols [w*16,+16) --
    {
        bf16x8 b3[8];
        const bf16x8* base3 = (const bf16x8*)w3f;
        #pragma unroll
        for (int k = 0; k < 8; ++k)
            b3[k] = base3[(w * 8 + k) * 64 + lane];
        f32x4 c3;
        {
            int colb = w * 16 + lq * 4;
            c3 = *(const f32x4*)(bf3v + colb) + *(const f32x4*)(gnn + colb);
        }

        #pragma unroll
        for (int mt = 0; mt < 4; ++mt) {
            bf16x8 a[8];
            #pragma unroll
            for (int k = 0; k < 8; ++k)
                a[k] = *(const bf16x8*)(&h2f[(mt * 8 + k) * 512 + lane * 8]);
            int grow = row0 + mt * 16 + lr;
            f32x4 acc = c3;
            #pragma unroll
            for (int k = 0; k < 8; ++k)
                acc = __builtin_amdgcn_mfma_f32_16x16x32_bf16(b3[k], a[k], acc, 0, 0, 0);
            if (grow < n)
                *(f32x4*)(out + (long)grow * 128 + w * 16 + lq * 4) = acc * 0.5f;
        }
    }
}

extern "C" void kernel_launch(void* const* d_in, const int* in_sizes, int n_in,
                              void* d_out, int out_size, void* d_ws, size_t ws_size,
                              hipStream_t stream)
{
    const float* x   = (const float*)d_in[0];
    const float* Wc1 = (const float*)d_in[1];
    const float* bc1 = (const float*)d_in[2];
    const float* Wc2 = (const float*)d_in[3];
    const float* bc2 = (const float*)d_in[4];
    const float* g1  = (const float*)d_in[5];
    const float* be1 = (const float*)d_in[6];
    const float* g2  = (const float*)d_in[7];
    const float* be2 = (const float*)d_in[8];
    const float* Wf1 = (const float*)d_in[9];
    const float* b1  = (const float*)d_in[10];
    const float* Wf2 = (const float*)d_in[11];
    const float* b2  = (const float*)d_in[12];
    const float* Wf3 = (const float*)d_in[13];
    const float* b3  = (const float*)d_in[14];
    int n = in_sizes[0] / 128;

    char* ws = (char*)d_ws;
    float* part = (float*)(ws + WS_PART);
    float* gnn  = (float*)(ws + WS_GNN);
    u16*   w1f  = (u16*)(ws + WS_W1F);
    u16*   w2f  = (u16*)(ws + WS_W2F);
    u16*   w3f  = (u16*)(ws + WS_W3F);
    float* warm = (float*)(ws + WS_WARM);

    k_prep<<<CS_BLOCKS + 128 + 32, 256, 0, stream>>>(
        x, Wf1, Wf2, Wf3, Wc1, Wc2, part, w1f, w2f, w3f, warm, n);
    k_gnn<<<1, 512, 0, stream>>>(part, Wc1, bc1, Wc2, bc2, g1, be1, g2, be2, gnn, n);
    int nb = (n + 63) / 64;
    k_main<<<nb, 512, 0, stream>>>(x, b1, b2, b3, w1f, w2f, w3f, gnn, (float*)d_out, n);
}

// Round 18
// 61.611 us; speedup vs baseline: 1.3822x; 1.0225x over previous
//
#include <hip/hip_runtime.h>
#include <hip/hip_bf16.h>

typedef float f32x4 __attribute__((ext_vector_type(4)));
typedef short bf16x8 __attribute__((ext_vector_type(8)));
typedef short bf16x4 __attribute__((ext_vector_type(4)));
typedef unsigned short u16;

#define CS_BLOCKS 512

// ws layout (bytes), all 512-aligned
#define WS_PART 0         // 512 * 128 f32 = 262144
#define WS_GNN  262144    // 128 f32 = 512
#define WS_W1F  262656    // 65536
#define WS_W2F  328192    // 131072
#define WS_W3F  459264    // 65536
#define WS_WARM 524800    // 128 B

__device__ __forceinline__ u16 f2bf(float f) {
    __hip_bfloat16 h = __float2bfloat16(f);
    return *reinterpret_cast<u16*>(&h);
}

__device__ __forceinline__ bf16x8 pack8(f32x4 a, f32x4 b) {
    union { bf16x8 v; __hip_bfloat162 h[4]; } u;
    u.h[0] = __float22bfloat162_rn(make_float2(a[0], a[1]));
    u.h[1] = __float22bfloat162_rn(make_float2(a[2], a[3]));
    u.h[2] = __float22bfloat162_rn(make_float2(b[0], b[1]));
    u.h[3] = __float22bfloat162_rn(make_float2(b[2], b[3]));
    return u.v;
}

__device__ __forceinline__ bf16x4 pack4(f32x4 a) {
    union { bf16x4 v; __hip_bfloat162 h[2]; } u;
    u.h[0] = __float22bfloat162_rn(make_float2(a[0], a[1]));
    u.h[1] = __float22bfloat162_rn(make_float2(a[2], a[3]));
    return u.v;
}

// ---------------------------------------------------------------------------
// Kernel A: [0,512): colsum partials of x (f32x4, 8 rows in flight, unroll 8).
//           [512,640): repack Wf1/Wf2/Wf3 -> MFMA-frag-ordered bf16.
//           [640,672): warm Wc1/Wc2 into L2/L3 for k_gnn's serial matvecs.
// ---------------------------------------------------------------------------
__global__ __launch_bounds__(256) void k_prep(
    const float* __restrict__ x,
    const float* __restrict__ Wf1, const float* __restrict__ Wf2,
    const float* __restrict__ Wf3,
    const float* __restrict__ Wc1, const float* __restrict__ Wc2,
    float* __restrict__ part, u16* __restrict__ w1f, u16* __restrict__ w2f,
    u16* __restrict__ w3f, float* __restrict__ warm, int n)
{
    __shared__ float smem[1024];
    int b = blockIdx.x, t = threadIdx.x;
    if (b < CS_BLOCKS) {
        int col4 = t & 31, rowo = t >> 5;       // col4: 16B chunk, rowo: 0..7
        int rpb = (n + CS_BLOCKS - 1) / CS_BLOCKS;
        int start = b * rpb;
        int end = min(start + rpb, n);
        f32x4 acc = {0.f, 0.f, 0.f, 0.f};
        #pragma unroll 8
        for (int r = start + rowo; r < end; r += 8)
            acc += *(const f32x4*)(x + (long)r * 128 + col4 * 4);
        *(f32x4*)&smem[rowo * 128 + col4 * 4] = acc;
        __syncthreads();
        if (t < 128) {
            float s = 0.f;
            #pragma unroll
            for (int i = 0; i < 8; ++i) s += smem[i * 128 + t];
            part[b * 128 + t] = s;
        }
    } else if (b < CS_BLOCKS + 128) {
        int e0 = ((b - CS_BLOCKS) * 256 + t) * 4; // 131072 elems total
        #pragma unroll
        for (int i = 0; i < 4; ++i) {
            int e = e0 + i;
            u16* dst; const float* src; int KS, NW;
            if (e < 32768)      { dst = w1f; src = Wf1; KS = 4; NW = 256; }
            else if (e < 98304) { dst = w2f; src = Wf2; KS = 8; NW = 256; e -= 32768; }
            else                { dst = w3f; src = Wf3; KS = 8; NW = 128; e -= 98304; }
            int fi = e >> 9, within = e & 511;
            int lane = within >> 3, j = within & 7;
            int nt = fi / KS, k = fi - nt * KS;
            int nn = nt * 16 + (lane & 15);
            int kk = k * 32 + ((lane >> 4) & 3) * 8 + j;
            dst[fi * 512 + within] = f2bf(src[kk * NW + nn]);
        }
    } else {
        // L2/L3 warm of Wc1 + Wc2: 2048 f32/block
        int idx = b - (CS_BLOCKS + 128);
        int base = idx * 2048 + t * 8;
        f32x4 a0, a1;
        if (base < 32768) {
            a0 = *(const f32x4*)(Wc1 + base);
            a1 = *(const f32x4*)(Wc1 + base + 4);
        } else {
            a0 = *(const f32x4*)(Wc2 + base - 32768);
            a1 = *(const f32x4*)(Wc2 + base - 32768 + 4);
        }
        float s = a0[0]+a0[1]+a0[2]+a0[3]+a1[0]+a1[1]+a1[2]+a1[3];
        smem[t] = s;
        __syncthreads();
        for (int o = 128; o > 0; o >>= 1) {
            if (t < o) smem[t] += smem[t + o];
            __syncthreads();
        }
        if (t == 0) warm[idx] = smem[0];
    }
}

// ---------------------------------------------------------------------------
// Kernel B: GCN chain — 512 threads; split-K matvecs; 8-wave reductions.
// (r17 version, verified −4 us.)
// ---------------------------------------------------------------------------
__device__ __forceinline__ float block_sum8(float v, float* wred, int t) {
    #pragma unroll
    for (int o = 32; o > 0; o >>= 1) v += __shfl_xor(v, o);
    if ((t & 63) == 0) wred[t >> 6] = v;
    __syncthreads();
    float s = 0.f;
    #pragma unroll
    for (int i = 0; i < 8; ++i) s += wred[i];
    __syncthreads();
    return s;
}

__global__ __launch_bounds__(512) void k_gnn(
    const float* __restrict__ part,
    const float* __restrict__ Wc1, const float* __restrict__ bc1,
    const float* __restrict__ Wc2, const float* __restrict__ bc2,
    const float* __restrict__ g1,  const float* __restrict__ be1,
    const float* __restrict__ g2,  const float* __restrict__ be2,
    float* __restrict__ gnn, int n)
{
    int t = threadIdx.x;
    __shared__ float cm[128];
    __shared__ float hv[256];
    __shared__ float red[512];
    __shared__ float wred[8];
    __shared__ float red32[32][128];

    {   // partial reduce: 512 partials of 128 cols, 32 row-groups
        int col8 = t & 15, rowo = t >> 4;        // rowo: 0..31
        f32x4 a0 = {0.f,0.f,0.f,0.f}, a1 = {0.f,0.f,0.f,0.f};
        #pragma unroll 8
        for (int p = rowo; p < CS_BLOCKS; p += 32) {   // 16 iters
            const f32x4* q = (const f32x4*)(part + p * 128 + col8 * 8);
            a0 += q[0]; a1 += q[1];
        }
        *(f32x4*)&red32[rowo][col8 * 8]     = a0;
        *(f32x4*)&red32[rowo][col8 * 8 + 4] = a1;
        __syncthreads();
        if (t < 128) {
            float s = 0.f;
            #pragma unroll
            for (int i = 0; i < 32; ++i) s += red32[i][t];
            cm[t] = s / (float)n;
        }
    }
    __syncthreads();

    // mv1 split-K2: col = t&255, half = t>>8; 64 iters each
    {
        int col = t & 255, half = t >> 8;
        float p = 0.f;
        #pragma unroll 8
        for (int i = half * 64; i < half * 64 + 64; ++i)
            p += cm[i] * Wc1[i * 256 + col];
        red[t] = p;
    }
    __syncthreads();
    float v = 0.f;
    bool act = (t < 256);
    if (act) v = fmaxf(bc1[t] + red[t] + red[t + 256], 0.f);

    // LN over 256 (upper threads masked)
    float mu = block_sum8(act ? v : 0.f, wred, t) * (1.f / 256.f);
    float d = v - mu;
    float var = block_sum8(act ? d * d : 0.f, wred, t) * (1.f / 256.f);
    if (act) hv[t] = d * rsqrtf(var + 1e-5f) * g1[t] + be1[t];
    __syncthreads();

    // mv2 split-K4: col = t&127, q4 = t>>7; 64 iters each
    {
        int col = t & 127, q4 = t >> 7;
        float p = 0.f;
        #pragma unroll 8
        for (int i = q4 * 64; i < q4 * 64 + 64; ++i)
            p += hv[i] * Wc2[i * 128 + col];
        red[t] = p;
    }
    __syncthreads();
    float v2 = 0.f;
    bool lo = (t < 128);
    if (lo) v2 = bc2[t] + red[t] + red[t + 128] + red[t + 256] + red[t + 384];

    // LN over 128
    float mu2 = block_sum8(lo ? v2 : 0.f, wred, t) * (1.f / 128.f);
    float d2 = v2 - mu2;
    float var2 = block_sum8(lo ? d2 * d2 : 0.f, wred, t) * (1.f / 128.f);
    if (lo) gnn[t] = d2 * rsqrtf(var2 + 1e-5f) * g2[t] + be2[t];
}

// ---------------------------------------------------------------------------
// Kernel C: fused 3-layer MLP — r17 structure (44.4 us verified) + T5:
// s_setprio(1) around each MFMA cluster. Rationale: 2 independent
// blocks/CU at different phases => cross-block role diversity (the attn-style
// regime where setprio measured +4-7%, vs null for lockstep). Everything
// else byte-identical to r17. Do NOT: hoist weight loads across barriers,
// merge L2 halves, alias h2 onto h1, split M across waves (all regressed).
// ---------------------------------------------------------------------------
__global__ __launch_bounds__(512) void k_main(
    const float* __restrict__ x,
    const float* __restrict__ bf1v, const float* __restrict__ bf2v,
    const float* __restrict__ bf3v,
    const u16* __restrict__ w1f, const u16* __restrict__ w2f,
    const u16* __restrict__ w3f,
    const float* __restrict__ gnn,
    float* __restrict__ out, int n)
{
    __shared__ __align__(16) u16 xsf[16 * 512];  // 16 KB
    __shared__ __align__(16) u16 h1f[32 * 512];  // 32 KB
    __shared__ __align__(16) u16 h2f[32 * 512];  // 32 KB

    int t = threadIdx.x;
    int row0 = blockIdx.x * 64;
    int w = t >> 6, lane = t & 63, lr = lane & 15, lq = lane >> 4;

    // ---- stage x tile -> xsf (fragment order): warp w fills frag w*2+it ----
    #pragma unroll
    for (int it = 0; it < 2; ++it) {
        int f = w * 2 + it;                      // frag = (mt = f>>2, k = f&3)
        int grow = row0 + (f >> 2) * 16 + lr;
        f32x4 f0 = {0.f,0.f,0.f,0.f}, f1 = {0.f,0.f,0.f,0.f};
        if (grow < n) {
            const float* p = x + (long)grow * 128 + (f & 3) * 32 + lq * 8;
            f0 = *(const f32x4*)p; f1 = *(const f32x4*)(p + 4);
        }
        *(bf16x8*)(&xsf[f * 512 + lane * 8]) = pack8(f0, f1);
    }
    __syncthreads();

    // ---- layer 1: h1 = relu(x @ Wf1 + bf1), wave cols [w*32, w*32+32) ----
    {
        bf16x8 b1[2][4];
        const bf16x8* base = (const bf16x8*)w1f;
        #pragma unroll
        for (int nt = 0; nt < 2; ++nt)
            #pragma unroll
            for (int k = 0; k < 4; ++k)
                b1[nt][k] = base[(((w * 2 + nt) * 4) + k) * 64 + lane];
        f32x4 bias1[2];
        #pragma unroll
        for (int nt = 0; nt < 2; ++nt)
            bias1[nt] = *(const f32x4*)(bf1v + w * 32 + nt * 16 + lq * 4);

        #pragma unroll
        for (int mt = 0; mt < 4; ++mt) {
            bf16x8 a[4];
            #pragma unroll
            for (int k = 0; k < 4; ++k)
                a[k] = *(const bf16x8*)(&xsf[(mt * 4 + k) * 512 + lane * 8]);
            __builtin_amdgcn_s_setprio(1);
            f32x4 accs[2];
            #pragma unroll
            for (int nt = 0; nt < 2; ++nt) {
                f32x4 acc = bias1[nt];
                #pragma unroll
                for (int k = 0; k < 4; ++k)   // swapped: C^T, lane=(col=lq*4+j, row=lr)
                    acc = __builtin_amdgcn_mfma_f32_16x16x32_bf16(b1[nt][k], a[k], acc, 0, 0, 0);
                accs[nt] = acc;
            }
            __builtin_amdgcn_s_setprio(0);
            #pragma unroll
            for (int nt = 0; nt < 2; ++nt) {
                f32x4 acc = accs[nt];
                acc[0] = fmaxf(acc[0], 0.f); acc[1] = fmaxf(acc[1], 0.f);
                acc[2] = fmaxf(acc[2], 0.f); acc[3] = fmaxf(acc[3], 0.f);
                int l = lr + 16 * (nt * 2 + (lq >> 1));
                *(bf16x4*)(&h1f[(mt * 8 + w) * 512 + l * 8 + (lq & 1) * 4]) = pack4(acc);
            }
        }
    }
    __syncthreads();

    // ---- layer 2: h2 = relu(h1 @ Wf2 + bf2), wave cols [w*32, w*32+32) ----
    {
        f32x4 bias2[2];
        #pragma unroll
        for (int nt = 0; nt < 2; ++nt)
            bias2[nt] = *(const f32x4*)(bf2v + w * 32 + nt * 16 + lq * 4);
        f32x4 acc2[4][2];
        #pragma unroll
        for (int mt = 0; mt < 4; ++mt)
            #pragma unroll
            for (int nt = 0; nt < 2; ++nt)
                acc2[mt][nt] = bias2[nt];

        const bf16x8* base2 = (const bf16x8*)w2f;
        bf16x8 b2a[2][4];
        #pragma unroll
        for (int nt = 0; nt < 2; ++nt)
            #pragma unroll
            for (int k = 0; k < 4; ++k)
                b2a[nt][k] = base2[(((w * 2 + nt) * 8) + k) * 64 + lane];

        #pragma unroll
        for (int mt = 0; mt < 4; ++mt) {          // half 0 (kk = 0..3)
            bf16x8 a[4];
            #pragma unroll
            for (int k = 0; k < 4; ++k)
                a[k] = *(const bf16x8*)(&h1f[(mt * 8 + k) * 512 + lane * 8]);
            __builtin_amdgcn_s_setprio(1);
            #pragma unroll
            for (int nt = 0; nt < 2; ++nt)
                #pragma unroll
                for (int k = 0; k < 4; ++k)
                    acc2[mt][nt] = __builtin_amdgcn_mfma_f32_16x16x32_bf16(b2a[nt][k], a[k], acc2[mt][nt], 0, 0, 0);
            __builtin_amdgcn_s_setprio(0);
        }

        bf16x8 b2b[2][4];
        #pragma unroll
        for (int nt = 0; nt < 2; ++nt)
            #pragma unroll
            for (int k = 0; k < 4; ++k)
                b2b[nt][k] = base2[(((w * 2 + nt) * 8) + 4 + k) * 64 + lane];

        #pragma unroll
        for (int mt = 0; mt < 4; ++mt) {          // half 1 (kk = 4..7)
            bf16x8 a[4];
            #pragma unroll
            for (int k = 0; k < 4; ++k)
                a[k] = *(const bf16x8*)(&h1f[(mt * 8 + 4 + k) * 512 + lane * 8]);
            __builtin_amdgcn_s_setprio(1);
            #pragma unroll
            for (int nt = 0; nt < 2; ++nt)
                #pragma unroll
                for (int k = 0; k < 4; ++k)
                    acc2[mt][nt] = __builtin_amdgcn_mfma_f32_16x16x32_bf16(b2b[nt][k], a[k], acc2[mt][nt], 0, 0, 0);
            __builtin_amdgcn_s_setprio(0);
        }

        // epilogue writes go to the separate h2f buffer — no guard needed
        #pragma unroll
        for (int mt = 0; mt < 4; ++mt) {
            #pragma unroll
            for (int nt = 0; nt < 2; ++nt) {
                f32x4 acc = acc2[mt][nt];
                acc[0] = fmaxf(acc[0], 0.f); acc[1] = fmaxf(acc[1], 0.f);
                acc[2] = fmaxf(acc[2], 0.f); acc[3] = fmaxf(acc[3], 0.f);
                int l = lr + 16 * (nt * 2 + (lq >> 1));
                *(bf16x4*)(&h2f[(mt * 8 + w) * 512 + l * 8 + (lq & 1) * 4]) = pack4(acc);
            }
        }
    }
    __syncthreads();

    // ---- layer 3: out = (h2 @ Wf3 + bf3 + gnn)*0.5, wave cols [w*16,+16) --
    {
        bf16x8 b3[8];
        const bf16x8* base3 = (const bf16x8*)w3f;
        #pragma unroll
        for (int k = 0; k < 8; ++k)
            b3[k] = base3[(w * 8 + k) * 64 + lane];
        f32x4 c3;
        {
            int colb = w * 16 + lq * 4;
            c3 = *(const f32x4*)(bf3v + colb) + *(const f32x4*)(gnn + colb);
        }

        #pragma unroll
        for (int mt = 0; mt < 4; ++mt) {
            bf16x8 a[8];
            #pragma unroll
            for (int k = 0; k < 8; ++k)
                a[k] = *(const bf16x8*)(&h2f[(mt * 8 + k) * 512 + lane * 8]);
            int grow = row0 + mt * 16 + lr;
            __builtin_amdgcn_s_setprio(1);
            f32x4 acc = c3;
            #pragma unroll
            for (int k = 0; k < 8; ++k)
                acc = __builtin_amdgcn_mfma_f32_16x16x32_bf16(b3[k], a[k], acc, 0, 0, 0);
            __builtin_amdgcn_s_setprio(0);
            if (grow < n)
                *(f32x4*)(out + (long)grow * 128 + w * 16 + lq * 4) = acc * 0.5f;
        }
    }
}

extern "C" void kernel_launch(void* const* d_in, const int* in_sizes, int n_in,
                              void* d_out, int out_size, void* d_ws, size_t ws_size,
                              hipStream_t stream)
{
    const float* x   = (const float*)d_in[0];
    const float* Wc1 = (const float*)d_in[1];
    const float* bc1 = (const float*)d_in[2];
    const float* Wc2 = (const float*)d_in[3];
    const float* bc2 = (const float*)d_in[4];
    const float* g1  = (const float*)d_in[5];
    const float* be1 = (const float*)d_in[6];
    const float* g2  = (const float*)d_in[7];
    const float* be2 = (const float*)d_in[8];
    const float* Wf1 = (const float*)d_in[9];
    const float* b1  = (const float*)d_in[10];
    const float* Wf2 = (const float*)d_in[11];
    const float* b2  = (const float*)d_in[12];
    const float* Wf3 = (const float*)d_in[13];
    const float* b3  = (const float*)d_in[14];
    int n = in_sizes[0] / 128;

    char* ws = (char*)d_ws;
    float* part = (float*)(ws + WS_PART);
    float* gnn  = (float*)(ws + WS_GNN);
    u16*   w1f  = (u16*)(ws + WS_W1F);
    u16*   w2f  = (u16*)(ws + WS_W2F);
    u16*   w3f  = (u16*)(ws + WS_W3F);
    float* warm = (float*)(ws + WS_WARM);

    k_prep<<<CS_BLOCKS + 128 + 32, 256, 0, stream>>>(
        x, Wf1, Wf2, Wf3, Wc1, Wc2, part, w1f, w2f, w3f, warm, n);
    k_gnn<<<1, 512, 0, stream>>>(part, Wc1, bc1, Wc2, bc2, g1, be1, g2, be2, gnn, n);
    int nb = (n + 63) / 64;
    k_main<<<nb, 512, 0, stream>>>(x, b1, b2, b3, w1f, w2f, w3f, gnn, (float*)d_out, n);
}